// Round 5
// baseline (384.068 us; speedup 1.0000x reference)
//
#include <hip/hip_runtime.h>
#include <hip/hip_bf16.h>

typedef __attribute__((ext_vector_type(8))) short short8;
typedef __attribute__((ext_vector_type(4))) float float4_;

__device__ __forceinline__ short f2b(float f) {
  union { __hip_bfloat16 h; short s; } u;
  u.h = __float2bfloat16(f);
  return u.s;
}
__device__ __forceinline__ float b2f(short s) {
  union { short s; __hip_bfloat16 h; } u;
  u.s = s;
  return __bfloat162float(u.h);
}
__device__ __forceinline__ short8 cvt8(float4_ lo, float4_ hi) {
  short8 r;
#pragma unroll
  for (int t = 0; t < 4; t++) { r[t] = f2b(lo[t]); r[t + 4] = f2b(hi[t]); }
  return r;
}

// fp32 -> bf16 elementwise, n multiple of 8.
__global__ __launch_bounds__(256) void f32_to_b16(
    const float* __restrict__ in, short* __restrict__ out, long n)
{
  const long i = ((long)blockIdx.x * 256 + threadIdx.x) * 8;
  if (i >= n) return;
  float4_ lo = *(const float4_*)&in[i];
  float4_ hi = *(const float4_*)&in[i + 4];
  *(short8*)&out[i] = cvt8(lo, hi);
}

// out[C][R] = bf16(in[R][C])^T; in fp32. 64x64 LDS tiles (stride 72: 16B-aligned).
__global__ __launch_bounds__(256) void transpose64(
    const float* __restrict__ in, short* __restrict__ out, int R, int C)
{
  __shared__ __align__(16) short T[64 * 72];
  const int tid = threadIdx.x;
  const int r0 = blockIdx.y * 64;
  const int c0 = blockIdx.x * 64;
  const int r  = tid >> 2;
  const int cp = (tid & 3) * 16;
#pragma unroll
  for (int g = 0; g < 4; g++) {
    float4_ v = *(const float4_*)&in[(long)(r0 + r) * C + c0 + cp + g * 4];
#pragma unroll
    for (int t = 0; t < 4; t++) T[(cp + g * 4 + t) * 72 + r] = f2b(v[t]);
  }
  __syncthreads();
  const int c  = tid >> 2;
  const int rp = (tid & 3) * 16;
  short8 w0 = *(const short8*)&T[c * 72 + rp];
  short8 w1 = *(const short8*)&T[c * 72 + rp + 8];
  *(short8*)&out[(long)(c0 + c) * R + r0 + rp] = w0;
  *(short8*)&out[(long)(c0 + c) * R + r0 + rp + 8] = w1;
}

// C[M,N] = A[M,K] @ B[N,K]^T (+ bias). A bf16 or fp32 (a_f32); B bf16.
// C bf16, or fp32 with fp32 bias when c_f32. 128x128 tile, 4 waves (2x2 of
// 64x64), BK=32, fp32 accum, plain-load staging (function proven R3==R4).
__global__ __launch_bounds__(256) void gemm_bt(
    const void* __restrict__ Av, int lda, int a_f32,
    const short* __restrict__ B,
    void* __restrict__ Cv, int ldc, int c_f32,
    int K, const float* __restrict__ bias)
{
  __shared__ __align__(16) short As[128 * 32];
  __shared__ __align__(16) short Bs[128 * 32];
  const int tid  = threadIdx.x;
  const int lane = tid & 63;
  const int w    = tid >> 6;
  const int quad = lane >> 4;
  const int l15  = lane & 15;
  const int wm   = (w >> 1) * 64;
  const int wn   = (w & 1) * 64;
  const int m0   = blockIdx.y * 128;
  const int n0   = blockIdx.x * 128;

  float4_ acc[4][4] = {};

  const int srow = tid >> 2;        // 0..63
  const int kp   = (tid & 3) * 8;   // k-part (elements)

  for (int k0 = 0; k0 < K; k0 += 32) {
    short8 a_lo, a_hi;
    if (a_f32) {
      const float* Af = (const float*)Av;
      float4_ l0 = *(const float4_*)&Af[(long)(m0 + srow) * lda + k0 + kp];
      float4_ l1 = *(const float4_*)&Af[(long)(m0 + srow) * lda + k0 + kp + 4];
      float4_ h0 = *(const float4_*)&Af[(long)(m0 + srow + 64) * lda + k0 + kp];
      float4_ h1 = *(const float4_*)&Af[(long)(m0 + srow + 64) * lda + k0 + kp + 4];
      a_lo = cvt8(l0, l1);
      a_hi = cvt8(h0, h1);
    } else {
      const short* As_ = (const short*)Av;
      a_lo = *(const short8*)&As_[(long)(m0 + srow) * lda + k0 + kp];
      a_hi = *(const short8*)&As_[(long)(m0 + srow + 64) * lda + k0 + kp];
    }
    short8 b_lo = *(const short8*)&B[(long)(n0 + srow) * K + k0 + kp];
    short8 b_hi = *(const short8*)&B[(long)(n0 + srow + 64) * K + k0 + kp];
    __syncthreads();  // previous iteration's LDS reads done
    *(short8*)&As[srow * 32 + kp]        = a_lo;
    *(short8*)&As[(srow + 64) * 32 + kp] = a_hi;
    *(short8*)&Bs[srow * 32 + kp]        = b_lo;
    *(short8*)&Bs[(srow + 64) * 32 + kp] = b_hi;
    __syncthreads();
    short8 a[4], b[4];
#pragma unroll
    for (int i = 0; i < 4; i++)
      a[i] = *(const short8*)&As[(wm + i * 16 + l15) * 32 + quad * 8];
#pragma unroll
    for (int j = 0; j < 4; j++)
      b[j] = *(const short8*)&Bs[(wn + j * 16 + l15) * 32 + quad * 8];
#pragma unroll
    for (int i = 0; i < 4; i++)
#pragma unroll
      for (int j = 0; j < 4; j++)
        acc[i][j] = __builtin_amdgcn_mfma_f32_16x16x32_bf16(a[i], b[j], acc[i][j], 0, 0, 0);
  }

#pragma unroll
  for (int i = 0; i < 4; i++) {
    const int rm = m0 + wm + i * 16 + quad * 4;
#pragma unroll
    for (int j = 0; j < 4; j++) {
      const int cn = n0 + wn + j * 16 + l15;
      if (c_f32) {
        float* C = (float*)Cv;
        const float bv = bias ? bias[cn] : 0.0f;
#pragma unroll
        for (int r = 0; r < 4; r++)
          C[(long)(rm + r) * ldc + cn] = acc[i][j][r] + bv;
      } else {
        short* C = (short*)Cv;
#pragma unroll
        for (int r = 0; r < 4; r++)
          C[(long)(rm + r) * ldc + cn] = f2b(acc[i][j][r]);
      }
    }
  }
}

// One workgroup per 128-row block: Q,K,V = qkv[rows +0..128, {0,1024,2048}+cols]
// S = QK^T/32, causal-mask, softmax (+1e-6), O = P V, written in-place into the
// Q columns (all Q reads complete in phase 1; each block touches only its rows).
__global__ __launch_bounds__(256) void attn_blockdiag(short* __restrict__ qkv)
{
  __shared__ __align__(16) short Qs[128 * 32];
  __shared__ __align__(16) short Ks[128 * 32];
  __shared__ __align__(16) short Ps[128 * 136];  // row stride 136 (272 B, 16B-aligned)

  const int tid  = threadIdx.x;
  const int lane = tid & 63;
  const int w    = tid >> 6;
  const int quad = lane >> 4;
  const int l15  = lane & 15;
  const long base = (long)blockIdx.x * 128 * 3072;

  // ---- Phase 1: S = Q K^T. wave w owns rows 32w..32w+31 (full 128 cols in-wave).
  float4_ acc[2][8] = {};
  const int srow = tid >> 2;
  const int kp   = (tid & 3) * 8;
  const short* Qg = qkv + base;
  const short* Kg = qkv + base + 1024;

  for (int k0 = 0; k0 < 1024; k0 += 32) {
    short8 q_lo = *(const short8*)&Qg[(long)srow * 3072 + k0 + kp];
    short8 q_hi = *(const short8*)&Qg[(long)(srow + 64) * 3072 + k0 + kp];
    short8 k_lo = *(const short8*)&Kg[(long)srow * 3072 + k0 + kp];
    short8 k_hi = *(const short8*)&Kg[(long)(srow + 64) * 3072 + k0 + kp];
    __syncthreads();
    *(short8*)&Qs[srow * 32 + kp]        = q_lo;
    *(short8*)&Qs[(srow + 64) * 32 + kp] = q_hi;
    *(short8*)&Ks[srow * 32 + kp]        = k_lo;
    *(short8*)&Ks[(srow + 64) * 32 + kp] = k_hi;
    __syncthreads();
    short8 a0 = *(const short8*)&Qs[(w * 32 + l15) * 32 + quad * 8];
    short8 a1 = *(const short8*)&Qs[(w * 32 + 16 + l15) * 32 + quad * 8];
#pragma unroll
    for (int j = 0; j < 8; j++) {
      short8 b = *(const short8*)&Ks[(j * 16 + l15) * 32 + quad * 8];
      acc[0][j] = __builtin_amdgcn_mfma_f32_16x16x32_bf16(a0, b, acc[0][j], 0, 0, 0);
      acc[1][j] = __builtin_amdgcn_mfma_f32_16x16x32_bf16(a1, b, acc[1][j], 0, 0, 0);
    }
  }
  __syncthreads();

  // ---- Phase 2: mask + softmax, in registers + 16-lane shuffles.
  const float scale = 0.03125f;  // 1024^-0.5
#pragma unroll
  for (int i = 0; i < 2; i++) {
#pragma unroll
    for (int r = 0; r < 4; r++) {
      const int rowq = w * 32 + i * 16 + quad * 4 + r;
      float s[8];
      float mx = -3.0e38f;
#pragma unroll
      for (int j = 0; j < 8; j++) {
        const int col = j * 16 + l15;
        const float v = acc[i][j][r] * scale;
        s[j] = (col <= rowq) ? v : -3.0e38f;
        mx = fmaxf(mx, s[j]);
      }
      mx = fmaxf(mx, __shfl_xor(mx, 1));
      mx = fmaxf(mx, __shfl_xor(mx, 2));
      mx = fmaxf(mx, __shfl_xor(mx, 4));
      mx = fmaxf(mx, __shfl_xor(mx, 8));
      float p[8];
      float sum = 0.0f;
#pragma unroll
      for (int j = 0; j < 8; j++) {
        p[j] = (s[j] > -1.0e38f) ? __expf(s[j] - mx) : 0.0f;
        sum += p[j];
      }
      sum += __shfl_xor(sum, 1);
      sum += __shfl_xor(sum, 2);
      sum += __shfl_xor(sum, 4);
      sum += __shfl_xor(sum, 8);
      const float inv = 1.0f / (sum + 1e-6f);
#pragma unroll
      for (int j = 0; j < 8; j++)
        Ps[rowq * 136 + j * 16 + l15] = f2b(p[j] * inv);  // C-layout -> A-layout via LDS
    }
  }
  __syncthreads();

  // ---- Phase 3: O = P V. A from LDS (b128), B (V columns) strided from global.
  const short* Vg = qkv + base + 2048;
  short* Op = qkv + base;  // in-place into Q columns
  for (int d0 = 0; d0 < 1024; d0 += 64) {
    float4_ o[2][4] = {};
#pragma unroll
    for (int kk = 0; kk < 4; kk++) {
      short8 a0 = *(const short8*)&Ps[(w * 32 + l15) * 136 + kk * 32 + quad * 8];
      short8 a1 = *(const short8*)&Ps[(w * 32 + 16 + l15) * 136 + kk * 32 + quad * 8];
      const int kb = kk * 32 + quad * 8;
#pragma unroll
      for (int j = 0; j < 4; j++) {
        const int d = d0 + j * 16 + l15;
        short8 b;
#pragma unroll
        for (int t = 0; t < 8; t++)
          b[t] = Vg[(long)(kb + t) * 3072 + d];
        o[0][j] = __builtin_amdgcn_mfma_f32_16x16x32_bf16(a0, b, o[0][j], 0, 0, 0);
        o[1][j] = __builtin_amdgcn_mfma_f32_16x16x32_bf16(a1, b, o[1][j], 0, 0, 0);
      }
    }
#pragma unroll
    for (int i = 0; i < 2; i++)
#pragma unroll
      for (int j = 0; j < 4; j++)
#pragma unroll
        for (int r = 0; r < 4; r++) {
          const int rq = w * 32 + i * 16 + quad * 4 + r;
          const int d  = d0 + j * 16 + l15;
          Op[(long)rq * 3072 + d] = f2b(o[i][j][r]);
        }
  }
}

extern "C" void kernel_launch(void* const* d_in, const int* in_sizes, int n_in,
                              void* d_out, int out_size, void* d_ws, size_t ws_size,
                              hipStream_t stream) {
  // Inputs fp32 (R2 bf16-read -> NaN). OUTPUT fp32 (reference returns fp32;
  // R3==R4 bit-identical absmax proved compute correct, I/O dtype was the bug).
  const float* x    = (const float*)d_in[0];  // [4,4096,1024]
  const float* Wqkv = (const float*)d_in[1];  // [1024,3072]
  const float* Wout = (const float*)d_in[2];  // [1024,1024] (= [N][K] for @W_out^T)
  const float* bout = (const float*)d_in[3];  // [1024]
  float* out = (float*)d_out;                 // [4,4096,1024] fp32

  char* ws = (char*)d_ws;
  short* WqkvT = (short*)ws;                    // [3072][1024] bf16:  6,291,456 B
  short* Woutb = (short*)(ws + 6291456);        // [1024][1024] bf16:  2,097,152 B
  short* qkv   = (short*)(ws + 8388608);        // bf16, up to [16384][3072]
  short* xb    = (short*)(ws + 8388608 + (size_t)16384 * 3072 * 2);  // [16384][1024]

  transpose64<<<dim3(48, 16), 256, 0, stream>>>(Wqkv, WqkvT, 1024, 3072);
  f32_to_b16<<<512, 256, 0, stream>>>(Wout, Woutb, 1048576L);

  if (ws_size >= 8388608 + (size_t)16384 * 3072 * 2 + (size_t)16384 * 1024 * 2) {
    // Tier A (143 MB): pre-convert x to bf16, full-width pipeline.
    f32_to_b16<<<8192, 256, 0, stream>>>(x, xb, 16777216L);
    gemm_bt<<<dim3(24, 128), 256, 0, stream>>>(xb, 1024, 0, WqkvT,
                                               qkv, 3072, 0, 1024, nullptr);
    attn_blockdiag<<<dim3(128), 256, 0, stream>>>(qkv);
    gemm_bt<<<dim3(8, 128), 256, 0, stream>>>(qkv, 3072, 0, Woutb,
                                              out, 1024, 1, 1024, bout);
  } else if (ws_size >= 8388608 + (size_t)16384 * 3072 * 2) {
    // Tier B (109 MB): full-width, gemm1 converts x fp32 -> bf16 while staging.
    gemm_bt<<<dim3(24, 128), 256, 0, stream>>>(x, 1024, 1, WqkvT,
                                               qkv, 3072, 0, 1024, nullptr);
    attn_blockdiag<<<dim3(128), 256, 0, stream>>>(qkv);
    gemm_bt<<<dim3(8, 128), 256, 0, stream>>>(qkv, 3072, 0, Woutb,
                                              out, 1024, 1, 1024, bout);
  } else {
    // Tier C (34 MB): per-batch chunks of 4096 rows.
    for (int c = 0; c < 4; c++) {
      const float* xc = x + (long)c * 4096 * 1024;
      float* outc = out + (long)c * 4096 * 1024;
      gemm_bt<<<dim3(24, 32), 256, 0, stream>>>(xc, 1024, 1, WqkvT,
                                                qkv, 3072, 0, 1024, nullptr);
      attn_blockdiag<<<dim3(32), 256, 0, stream>>>(qkv);
      gemm_bt<<<dim3(8, 32), 256, 0, stream>>>(qkv, 3072, 0, Woutb,
                                               outc, 1024, 1, 1024, bout);
    }
  }
}